// Round 3
// baseline (692.069 us; speedup 1.0000x reference)
//
#include <hip/hip_runtime.h>

typedef unsigned short u16;
typedef unsigned int u32;
typedef unsigned long long u64;
typedef __bf16 bf16_t;
typedef __bf16 bf16x8 __attribute__((ext_vector_type(8)));
typedef float f32x4 __attribute__((ext_vector_type(4)));
typedef u32 u32x4 __attribute__((ext_vector_type(4)));   // native vector: OK for NT builtins

#define NN 5000
#define NF 512
#define NH 64
#define HEADS 8
#define NCLS 40
#define CAP 128
#define LRELU 0.2f

#define BM_BLKS 1250                 // 4 waves/block-item, wave per adj row
#define G1_BLKS (79 * HEADS)         // 632 GEMM items; adj items appended after
#define FUSED_MAXBLK 512             // 2 blocks/CU — co-residency safe up to 256 VGPR

// ---- dtype probe: adj[0][0]==1.0 always (self-loop). fp32 word0=0x3F800000 (low16==0);
// ---- packed-bf16 word0 low half = 0x3F80 != 0. (fp32 path taken on this harness.)
__device__ __forceinline__ bool adj_is_bf16(const void* adj) {
    return ((*(const u32*)adj) & 0xFFFFu) != 0u;
}
__device__ __forceinline__ u16 rne_bf16(float f) {
    u32 u = __float_as_uint(f);
    u += 0x7FFFu + ((u >> 16) & 1u);
    return (u16)(u >> 16);
}
__device__ __forceinline__ float up_bf16(u16 h) {
    return __uint_as_float((u32)h << 16);
}
__device__ __forceinline__ u32x4 ntload4(const void* p, int idx) {
    return __builtin_nontemporal_load(((const u32x4*)p) + idx);
}

// ---- shared-memory phase layouts (union; max 12.3 KB) ----
struct SmemA { float f1s[4][64]; float f2s[4][64]; };
struct SmemB { int s_nbr[CAP]; float s_p[8][CAP]; };
struct SmemC { float sh[4 * 512]; float ps[4][4][64]; };
struct SmemD { float s_alpha[4][CAP]; int s_nbr[4][CAP]; float s_h2[4][NH];
               float s_h3[4][200]; float ps2[2][4][NCLS]; };
union alignas(16) SmemU { SmemA pa; SmemB pb; SmemC pc; SmemD pd; };

// ---- device-scope grid barrier (all blocks co-resident; counter zeroed via memsetAsync) ----
__device__ __forceinline__ void gsync(u32* bar, int k, int nblk) {
    __syncthreads();
    if (threadIdx.x == 0) {
        __threadfence();                                        // release my writes device-wide
        __hip_atomic_fetch_add(&bar[k], 1u, __ATOMIC_ACQ_REL, __HIP_MEMORY_SCOPE_AGENT);
        while (__hip_atomic_load(&bar[k], __ATOMIC_ACQUIRE, __HIP_MEMORY_SCOPE_AGENT) < (u32)nblk)
            __builtin_amdgcn_s_sleep(2);
        __threadfence();                                        // invalidate before consuming
    }
    __syncthreads();
}

// ---------------- phase 0: canonicalize x (bf16), W_h (MFMA-fragment order), params ----
// whc fragment layout: element (h,f,o) -> (h*16+s)*2048 + (o>>4)*512 + quad*128 + (o&15)*8 + j
// with s=f>>5, quad=(f>>3)&3, j=f&7.  gemm1 thread t loads its bf16x8 B-fragment for k-step s
// as ONE 16B coalesced vector load at (h*16+s)*2048 + t*8.
__device__ void dev_cvt(int gtid, int gstr, bool isb,
                        const void* __restrict__ x, const void* __restrict__ W_h,
                        const void* a_h, const void* W_o, const void* a_o,
                        const void* f1w, const void* f1b, const void* f2w, const void* f2b,
                        u16* __restrict__ xc, u16* __restrict__ whc,
                        float* a_hc, float* W_oc, float* a_oc,
                        float* f1wc, float* f1bc, float* f2wc, float* f2bc) {
    const int X4 = NN * NF / 4;                          // 640,000
    const int T4 = X4 + HEADS * NF * NH / 4;             // 705,536
    for (int i = gtid; i < T4; i += gstr) {
        if (i < X4) {
            ushort4 o;
            if (isb) {
                o = ((const ushort4*)x)[i];              // already bf16: copy 8 B
            } else {
                u32x4 vv = ntload4(x, i);
                o.x = rne_bf16(__uint_as_float(vv[0])); o.y = rne_bf16(__uint_as_float(vv[1]));
                o.z = rne_bf16(__uint_as_float(vv[2])); o.w = rne_bf16(__uint_as_float(vv[3]));
            }
            ((ushort4*)xc)[i] = o;
        } else {
            const int iw = i - X4;                       // ushort4 index into W_h
            u16 q[4];
            if (isb) {
                ushort4 vv = ((const ushort4*)W_h)[iw];
                q[0] = vv.x; q[1] = vv.y; q[2] = vv.z; q[3] = vv.w;
            } else {
                u32x4 vv = ntload4(W_h, iw);
                q[0] = rne_bf16(__uint_as_float(vv[0])); q[1] = rne_bf16(__uint_as_float(vv[1]));
                q[2] = rne_bf16(__uint_as_float(vv[2])); q[3] = rne_bf16(__uint_as_float(vv[3]));
            }
            const int e0 = iw * 4;                       // flat (h,f,o), 4 consecutive o
            const int h = e0 >> 15;
            const int rem = e0 & 32767;
            const int f = rem >> 6, o0 = rem & 63;
            const int base = (h * 16 + (f >> 5)) * 2048 + ((f >> 3) & 3) * 128 + (f & 7);
            #pragma unroll
            for (int k = 0; k < 4; ++k) {
                const int o = o0 + k;
                whc[base + (o >> 4) * 512 + (o & 15) * 8] = q[k];
            }
        }
    }
    const int s0 = HEADS * 2 * NH, s1 = HEADS * NH * NH, s2 = 2 * NH,
              s3 = NH * 200, s4 = 200, s5 = 200 * NCLS, s6 = NCLS;
    const int total = s0 + s1 + s2 + s3 + s4 + s5 + s6;  // 54,960
    for (int i = gtid; i < total; i += gstr) {
        const void* src; float* dst; int off = i;
        if (off < s0) { src = a_h; dst = a_hc; }
        else if ((off -= s0) < s1) { src = W_o;  dst = W_oc; }
        else if ((off -= s1) < s2) { src = a_o;  dst = a_oc; }
        else if ((off -= s2) < s3) { src = f1w;  dst = f1wc; }
        else if ((off -= s3) < s4) { src = f1b;  dst = f1bc; }
        else if ((off -= s4) < s5) { src = f2w;  dst = f2wc; }
        else { off -= s5;           src = f2b;  dst = f2bc; }
        dst[off] = isb ? up_bf16(((const u16*)src)[off]) : ((const float*)src)[off];
    }
}

// ---------------- phase A item: Wh = x @ W_h tile (bf16 MFMA) + f1/f2 epilogue ----------
// C/D mapping row=(lane>>4)*4+r, col=lane&15. Wh stored NODE-MAJOR [n][h*64+o].
__device__ void dev_gemm1_item(int b, const bf16_t* __restrict__ x,
                               const bf16_t* __restrict__ Wf, const float* __restrict__ a_h,
                               float* __restrict__ Wh, float* __restrict__ f1,
                               float* __restrict__ f2, SmemA& sm) {
    const int lane = threadIdx.x & 63;
    const int wid  = threadIdx.x >> 6;
    const int rg = b % 79;                // 79*64 = 5056 rows, guarded
    const int h  = b / 79;
    const int quad = lane >> 4;
    const int lr   = lane & 15;
    const int kq   = quad * 8;
    const int nCol = wid * 16 + lr;

    const bf16_t* Bf = Wf + (size_t)h * (16 * 2048) + threadIdx.x * 8;
    bf16x8 bfrag[16];
    #pragma unroll
    for (int s = 0; s < 16; ++s) bfrag[s] = *(const bf16x8*)(Bf + s * 2048);

    const float a1c = a_h[h * 128 + nCol];
    const float a2c = a_h[h * 128 + NH + nCol];

    for (int t = 0; t < 4; ++t) {
        const int rb = rg * 64 + t * 16;
        int row  = rb + lr;
        int rowc = row < NN ? row : NN - 1;
        const bf16_t* xp = x + (size_t)rowc * NF + kq;
        f32x4 acc = {0.f, 0.f, 0.f, 0.f};
        #pragma unroll
        for (int s = 0; s < 16; ++s) {
            bf16x8 a = *(const bf16x8*)(xp + s * 32);
            acc = __builtin_amdgcn_mfma_f32_16x16x32_bf16(a, bfrag[s], acc, 0, 0, 0);
        }
        #pragma unroll
        for (int r = 0; r < 4; ++r) {
            int gr = rb + quad * 4 + r;
            if (gr < NN) Wh[(size_t)gr * (HEADS * NH) + h * NH + nCol] = acc[r];
            float p1 = acc[r] * a1c, p2 = acc[r] * a2c;
            #pragma unroll
            for (int o = 8; o; o >>= 1) { p1 += __shfl_xor(p1, o); p2 += __shfl_xor(p2, o); }
            if (lr == 0) { sm.f1s[wid][t * 16 + quad * 4 + r] = p1; sm.f2s[wid][t * 16 + quad * 4 + r] = p2; }
        }
    }
    __syncthreads();
    if (wid == 0) {
        int gr = rg * 64 + lane;
        if (gr < NN) {
            f1[h * NN + gr] = sm.f1s[0][lane] + sm.f1s[1][lane] + sm.f1s[2][lane] + sm.f1s[3][lane];
            f2[h * NN + gr] = sm.f2s[0][lane] + sm.f2s[1][lane] + sm.f2s[2][lane] + sm.f2s[3][lane];
        }
    }
    __syncthreads();                      // LDS reuse across grid-stride items
}

// ---------------- phase A item: adjacency rows -> neighbor lists (wave per row) ----------
__device__ void dev_adj_item(int a, const void* __restrict__ adj, bool isb,
                             int* __restrict__ nbr, int* __restrict__ deg) {
    const int lane = threadIdx.x & 63;
    const int wid  = threadIdx.x >> 6;
    const int r = a * 4 + wid;                           // exact 5000
    u64 my0 = 0ull, my1 = 0ull;                          // lane holds word `lane`, `lane+64`
    if (!isb) {
        const float* row = (const float*)adj + (size_t)r * NN;     // 1250 u32x4 chunks
        #pragma unroll
        for (int pass = 0; pass < 2; ++pass) {
            u32x4 v[10];
            #pragma unroll
            for (int k = 0; k < 10; ++k) {
                int c = (pass * 10 + k) * 64 + lane;
                v[k] = (c < 1250) ? ntload4(row, c) : (u32x4){0u, 0u, 0u, 0u};
            }
            #pragma unroll
            for (int k = 0; k < 10; ++k) {
                int i = pass * 10 + k;
                #pragma unroll
                for (int j = 0; j < 4; ++j) {
                    u64 m = __ballot(v[k][j] != 0u);     // wave-uniform
                    int w = i * 4 + j;
                    if (w == lane)      my0 = m;
                    if (w == lane + 64) my1 = m;
                }
            }
        }
    } else {
        const u16* row = (const u16*)adj + (size_t)r * NN;         // 625 u32x4 chunks
        u32x4 v[10];
        #pragma unroll
        for (int k = 0; k < 10; ++k) {
            int c = k * 64 + lane;
            v[k] = (c < 625) ? ntload4(row, c) : (u32x4){0u, 0u, 0u, 0u};
        }
        #pragma unroll
        for (int k = 0; k < 10; ++k) {
            #pragma unroll
            for (int j = 0; j < 4; ++j) {
                u64 mlo = __ballot((v[k][j] & 0xFFFFu) != 0u);
                u64 mhi = __ballot((v[k][j] >> 16) != 0u);
                int wl = k * 8 + 2 * j, wh = wl + 1;
                if (wl == lane)      my0 = mlo;
                if (wl == lane + 64) my1 = mlo;
                if (wh == lane)      my0 = mhi;
                if (wh == lane + 64) my1 = mhi;
            }
        }
    }
    // decode: popc prefix-scan over 128 lane-words, emit global neighbor list
    int* nrow = nbr + (size_t)r * CAP;
    int pc = __popcll(my0);
    int scan = pc;
    #pragma unroll
    for (int o = 1; o < 64; o <<= 1) {
        int t2 = __shfl_up(scan, o);
        if (lane >= o) scan += t2;
    }
    int off = scan - pc;
    {
        const int w = lane;
        u64 mw = my0;
        while (mw) {
            int bb = __ffsll(mw) - 1;
            mw &= mw - 1;
            int elem = !isb ? ((w >> 2) * 64 + bb) * 4 + (w & 3)
                            : ((w >> 3) * 64 + bb) * 8 + (w & 7);
            if (off < CAP) nrow[off] = elem;
            ++off;
        }
    }
    const int base = __shfl(scan, 63);
    int pc1 = __popcll(my1);
    int scan1 = pc1;
    #pragma unroll
    for (int o = 1; o < 64; o <<= 1) {
        int t2 = __shfl_up(scan1, o);
        if (lane >= o) scan1 += t2;
    }
    int off1 = base + scan1 - pc1;
    {
        const int w = lane + 64;
        u64 mw = my1;
        while (mw) {
            int bb = __ffsll(mw) - 1;
            mw &= mw - 1;
            int elem = !isb ? ((w >> 2) * 64 + bb) * 4 + (w & 3)
                            : ((w >> 3) * 64 + bb) * 8 + (w & 7);
            if (off1 < CAP) nrow[off1] = elem;
            ++off1;
        }
    }
    const int total = base + __shfl(scan1, 63);
    if (lane == 0) deg[r] = total < CAP ? total : CAP;
}

// ---------------- phase B: ALL-heads layer-1 attention for one node ----------------
__device__ void dev_agg1_node(int n, const int* __restrict__ nbr, const int* __restrict__ deg,
                              const float* __restrict__ Wh, const float* __restrict__ f1,
                              const float* __restrict__ f2, float* __restrict__ h1, SmemB& sm) {
    const int lane = threadIdx.x & 63;
    const int wid  = threadIdx.x >> 6;
    const int d = deg[n];
    for (int i = threadIdx.x; i < d; i += 256) sm.s_nbr[i] = nbr[(size_t)n * CAP + i];
    __syncthreads();

    const int ha = wid, hb = wid + 4;
    const int nb0 = (lane < d) ? sm.s_nbr[lane] : 0;
    const int nb1 = (lane + 64 < d) ? sm.s_nbr[lane + 64] : 0;
    const float f10 = f1[ha * NN + n], f11 = f1[hb * NN + n];
    const float* f2ha = f2 + (size_t)ha * NN;
    const float* f2hb = f2 + (size_t)hb * NN;

    float e00 = -INFINITY, e01 = -INFINITY, e10 = -INFINITY, e11 = -INFINITY;
    if (lane < d) {
        float a = f10 + f2ha[nb0]; e00 = a > 0.f ? a : LRELU * a;
        float b = f11 + f2hb[nb0]; e10 = b > 0.f ? b : LRELU * b;
    }
    if (lane + 64 < d) {
        float a = f10 + f2ha[nb1]; e01 = a > 0.f ? a : LRELU * a;
        float b = f11 + f2hb[nb1]; e11 = b > 0.f ? b : LRELU * b;
    }
    float mx0 = fmaxf(e00, e01), mx1 = fmaxf(e10, e11);
    #pragma unroll
    for (int o = 32; o; o >>= 1) {
        mx0 = fmaxf(mx0, __shfl_xor(mx0, o));
        mx1 = fmaxf(mx1, __shfl_xor(mx1, o));
    }
    float p00 = lane < d ? expf(e00 - mx0) : 0.f;
    float p01 = lane + 64 < d ? expf(e01 - mx0) : 0.f;
    float p10 = lane < d ? expf(e10 - mx1) : 0.f;
    float p11 = lane + 64 < d ? expf(e11 - mx1) : 0.f;
    float sm0 = p00 + p01, sm1 = p10 + p11;
    #pragma unroll
    for (int o = 32; o; o >>= 1) { sm0 += __shfl_xor(sm0, o); sm1 += __shfl_xor(sm1, o); }

    const float i0 = 1.f / sm0, i1 = 1.f / sm1;          // fold 1/sum into alpha
    sm.s_p[ha][lane] = p00 * i0; sm.s_p[ha][lane + 64] = p01 * i0;
    sm.s_p[hb][lane] = p10 * i1; sm.s_p[hb][lane + 64] = p11 * i1;
    __syncthreads();                                     // gather reads other waves' alphas

    // gather: wave covers heads (2*wid, 2*wid+1); lane -> col pair 2*lane of 128
    const float* ap = sm.s_p[2 * wid + (lane >> 5)];
    const float* wp = Wh + wid * 128 + 2 * lane;
    float A0x = 0.f, A0y = 0.f, A1x = 0.f, A1y = 0.f;
    float A2x = 0.f, A2y = 0.f, A3x = 0.f, A3y = 0.f;
    int j = 0;
    for (; j + 8 <= d; j += 8) {
        #pragma unroll
        for (int u = 0; u < 8; ++u) {
            const float2 v = *(const float2*)(wp + (size_t)sm.s_nbr[j + u] * (HEADS * NH));
            const float a = ap[j + u];
            if ((u & 3) == 0)      { A0x += a * v.x; A0y += a * v.y; }
            else if ((u & 3) == 1) { A1x += a * v.x; A1y += a * v.y; }
            else if ((u & 3) == 2) { A2x += a * v.x; A2y += a * v.y; }
            else                   { A3x += a * v.x; A3y += a * v.y; }
        }
    }
    for (; j < d; ++j) {
        const float2 v = *(const float2*)(wp + (size_t)sm.s_nbr[j] * (HEADS * NH));
        const float a = ap[j];
        A0x += a * v.x; A0y += a * v.y;
    }
    float hx = A0x + A1x + A2x + A3x;
    float hy = A0y + A1y + A2y + A3y;
    hx = hx > 0.f ? hx : expf(hx) - 1.f;                 // ELU
    hy = hy > 0.f ? hy : expf(hy) - 1.f;
    *(float2*)(h1 + (size_t)n * (HEADS * NH) + wid * 128 + 2 * lane) = make_float2(hx, hy);
    __syncthreads();                                     // LDS reuse across items
}

// ---------------- phase C: Wh2 = h1 @ W_o + g1/g2 — 4 nodes/item ----------------
__device__ void dev_gemm2_item(int it, const float* __restrict__ h1, const float* __restrict__ W_o,
                               const float* __restrict__ a_o, float* __restrict__ Wh2,
                               float* __restrict__ g1, float* __restrict__ g2, SmemC& sm) {
    const int t = threadIdx.x;
    const int n0 = it * 4;
    const float4* src = (const float4*)(h1 + (size_t)n0 * 512);
    ((float4*)sm.sh)[t]       = src[t];
    ((float4*)sm.sh)[t + 256] = src[t + 256];
    __syncthreads();
    const int o = t & 63, part = t >> 6;
    float a0 = 0.f, a1 = 0.f, a2 = 0.f, a3 = 0.f;
    const float* wo = W_o + part * 128 * 64 + o;
    const float* s0 = sm.sh + part * 128;
    #pragma unroll 4
    for (int f = 0; f < 128; ++f) {
        float w = wo[f * 64];
        a0 += s0[f] * w; a1 += s0[512 + f] * w; a2 += s0[1024 + f] * w; a3 += s0[1536 + f] * w;
    }
    sm.ps[part][0][o] = a0; sm.ps[part][1][o] = a1; sm.ps[part][2][o] = a2; sm.ps[part][3][o] = a3;
    __syncthreads();
    const int nd = t >> 6;
    float w2 = sm.ps[0][nd][o] + sm.ps[1][nd][o] + sm.ps[2][nd][o] + sm.ps[3][nd][o];
    Wh2[(size_t)(n0 + nd) * 64 + o] = w2;
    float p1 = w2 * a_o[o], p2 = w2 * a_o[64 + o];
    #pragma unroll
    for (int s = 32; s; s >>= 1) { p1 += __shfl_xor(p1, s); p2 += __shfl_xor(p2, s); }
    if (o == 0) { g1[n0 + nd] = p1; g2[n0 + nd] = p2; }
    __syncthreads();                                     // LDS reuse across items
}

// ---------------- phase D: layer-2 attention + aggregation + MLP head ----------------
__device__ void dev_agg2_item(int it, const float* __restrict__ Wh2, const float* __restrict__ g1,
                              const float* __restrict__ g2, const int* __restrict__ nbr,
                              const int* __restrict__ deg, const float* __restrict__ fc1_w,
                              const float* __restrict__ fc1_b, const float* __restrict__ fc2_w,
                              const float* __restrict__ fc2_b, float* __restrict__ out, SmemD& sm) {
    const int lane = threadIdx.x & 63;
    const int wid  = threadIdx.x >> 6;
    const int t = threadIdx.x;
    const int n0 = it * 4;
    const int n = n0 + wid;
    const int d = deg[n];
    const int* nb = nbr + (size_t)n * CAP;
    const float gn = g1[n];

    float mx = -INFINITY;
    for (int j = lane; j < d; j += 64) {
        int m = nb[j];
        sm.s_nbr[wid][j] = m;
        float e = gn + g2[m];
        e = e > 0.f ? e : LRELU * e;
        sm.s_alpha[wid][j] = e;
        mx = fmaxf(mx, e);
    }
    #pragma unroll
    for (int o = 32; o; o >>= 1) mx = fmaxf(mx, __shfl_xor(mx, o));
    float smv = 0.f;
    for (int j = lane; j < d; j += 64) {
        float p = expf(sm.s_alpha[wid][j] - mx);
        sm.s_alpha[wid][j] = p;
        smv += p;
    }
    #pragma unroll
    for (int o = 32; o; o >>= 1) smv += __shfl_xor(smv, o);

    float acc0 = 0.f, acc1 = 0.f, acc2 = 0.f, acc3 = 0.f;
    int j = 0;
    for (; j + 4 <= d; j += 4) {
        acc0 += sm.s_alpha[wid][j]     * Wh2[(size_t)sm.s_nbr[wid][j]     * NH + lane];
        acc1 += sm.s_alpha[wid][j + 1] * Wh2[(size_t)sm.s_nbr[wid][j + 1] * NH + lane];
        acc2 += sm.s_alpha[wid][j + 2] * Wh2[(size_t)sm.s_nbr[wid][j + 2] * NH + lane];
        acc3 += sm.s_alpha[wid][j + 3] * Wh2[(size_t)sm.s_nbr[wid][j + 3] * NH + lane];
    }
    for (; j < d; ++j) acc0 += sm.s_alpha[wid][j] * Wh2[(size_t)sm.s_nbr[wid][j] * NH + lane];
    sm.s_h2[wid][lane] = (acc0 + acc1 + acc2 + acc3) / smv;
    __syncthreads();

    if (t < 200) {
        float b0 = 0.f, b1 = 0.f, b2 = 0.f, b3 = 0.f;
        #pragma unroll 4
        for (int f = 0; f < NH; ++f) {
            float w = fc1_w[f * 200 + t];
            b0 += sm.s_h2[0][f] * w; b1 += sm.s_h2[1][f] * w;
            b2 += sm.s_h2[2][f] * w; b3 += sm.s_h2[3][f] * w;
        }
        float bb = fc1_b[t];
        b0 += bb; b1 += bb; b2 += bb; b3 += bb;
        sm.s_h3[0][t] = b0 > 0.f ? b0 : expf(b0) - 1.f;
        sm.s_h3[1][t] = b1 > 0.f ? b1 : expf(b1) - 1.f;
        sm.s_h3[2][t] = b2 > 0.f ? b2 : expf(b2) - 1.f;
        sm.s_h3[3][t] = b3 > 0.f ? b3 : expf(b3) - 1.f;
    }
    __syncthreads();

    if (t < 80) {
        const int o = t % 40, fh = t / 40;
        float c0 = 0.f, c1 = 0.f, c2 = 0.f, c3 = 0.f;
        #pragma unroll 4
        for (int f = fh * 100; f < fh * 100 + 100; ++f) {
            float w = fc2_w[f * NCLS + o];
            c0 += sm.s_h3[0][f] * w; c1 += sm.s_h3[1][f] * w;
            c2 += sm.s_h3[2][f] * w; c3 += sm.s_h3[3][f] * w;
        }
        sm.ps2[fh][0][o] = c0; sm.ps2[fh][1][o] = c1; sm.ps2[fh][2][o] = c2; sm.ps2[fh][3][o] = c3;
    }
    __syncthreads();
    if (t < 160) {
        const int nd = t / 40, o = t % 40;
        out[(size_t)(n0 + nd) * NCLS + o] = sm.ps2[0][nd][o] + sm.ps2[1][nd][o] + fc2_b[o];
    }
    __syncthreads();                                     // LDS reuse across items
}

// ================= fused persistent kernel: 5 phases, 4 grid barriers =================
__global__ __launch_bounds__(256) void fused(
        const void* __restrict__ x, const void* __restrict__ adj,
        const void* __restrict__ W_h, const void* a_h, const void* W_o, const void* a_o,
        const void* f1w, const void* f1b, const void* f2w, const void* f2b,
        u16* __restrict__ xc, u16* __restrict__ whc,
        float* a_hc, float* W_oc, float* a_oc,
        float* f1wc, float* f1bc, float* f2wc, float* f2bc,
        int* __restrict__ nbr, int* __restrict__ deg,
        float* __restrict__ Wh, float* __restrict__ f1, float* __restrict__ f2,
        float* __restrict__ h1, float* __restrict__ Wh2,
        float* __restrict__ g1, float* __restrict__ g2,
        float* __restrict__ out, u32* bar, int nblk) {
    __shared__ SmemU sm;
    const bool isb = adj_is_bf16(adj);
    const int gtid = blockIdx.x * 256 + threadIdx.x;
    const int gstr = nblk * 256;

    dev_cvt(gtid, gstr, isb, x, W_h, a_h, W_o, a_o, f1w, f1b, f2w, f2b,
            xc, whc, a_hc, W_oc, a_oc, f1wc, f1bc, f2wc, f2bc);
    gsync(bar, 0, nblk);

    for (int it = blockIdx.x; it < G1_BLKS + BM_BLKS; it += nblk) {
        if (it < G1_BLKS) dev_gemm1_item(it, (const bf16_t*)xc, (const bf16_t*)whc, a_hc,
                                         Wh, f1, f2, sm.pa);
        else              dev_adj_item(it - G1_BLKS, adj, isb, nbr, deg);
    }
    gsync(bar, 1, nblk);

    for (int n = blockIdx.x; n < NN; n += nblk)
        dev_agg1_node(n, nbr, deg, Wh, f1, f2, h1, sm.pb);
    gsync(bar, 2, nblk);

    for (int it = blockIdx.x; it < NN / 4; it += nblk)
        dev_gemm2_item(it, h1, W_oc, a_oc, Wh2, g1, g2, sm.pc);
    gsync(bar, 3, nblk);

    for (int it = blockIdx.x; it < NN / 4; it += nblk)
        dev_agg2_item(it, Wh2, g1, g2, nbr, deg, f1wc, f1bc, f2wc, f2bc, out, sm.pd);
}

// ================= standalone fallback kernels (if occupancy query fails) =================
__global__ __launch_bounds__(256) void cvt_all(const void* x, const void* W_h, const void* adj,
                                               const void* a_h, const void* W_o, const void* a_o,
                                               const void* f1w, const void* f1b,
                                               const void* f2w, const void* f2b,
                                               u16* xc, u16* whc, float* a_hc, float* W_oc,
                                               float* a_oc, float* f1wc, float* f1bc,
                                               float* f2wc, float* f2bc) {
    dev_cvt(blockIdx.x * 256 + threadIdx.x, gridDim.x * 256, adj_is_bf16(adj),
            x, W_h, a_h, W_o, a_o, f1w, f1b, f2w, f2b,
            xc, whc, a_hc, W_oc, a_oc, f1wc, f1bc, f2wc, f2bc);
}
__global__ __launch_bounds__(256) void gemm1_f(const bf16_t* x, const bf16_t* Wf,
                                               const float* a_h, const void* adj,
                                               int* nbr, int* deg,
                                               float* Wh, float* f1, float* f2) {
    __shared__ SmemA sma;
    const int b = blockIdx.x;
    if (b < G1_BLKS) dev_gemm1_item(b, x, Wf, a_h, Wh, f1, f2, sma);
    else             dev_adj_item(b - G1_BLKS, adj, adj_is_bf16(adj), nbr, deg);
}
__global__ __launch_bounds__(256) void agg1f(const int* nbr, const int* deg, const float* Wh,
                                             const float* f1, const float* f2, float* h1) {
    __shared__ SmemB smb;
    dev_agg1_node(blockIdx.x, nbr, deg, Wh, f1, f2, h1, smb);
}
__global__ __launch_bounds__(256) void gemm2_4(const float* h1, const float* W_o, const float* a_o,
                                               float* Wh2, float* g1, float* g2) {
    __shared__ SmemC smc;
    dev_gemm2_item(blockIdx.x, h1, W_o, a_o, Wh2, g1, g2, smc);
}
__global__ __launch_bounds__(256) void agg2_mlp(const float* Wh2, const float* g1, const float* g2,
                                                const int* nbr, const int* deg,
                                                const float* fc1_w, const float* fc1_b,
                                                const float* fc2_w, const float* fc2_b,
                                                float* out) {
    __shared__ SmemD smd;
    dev_agg2_item(blockIdx.x, Wh2, g1, g2, nbr, deg, fc1_w, fc1_b, fc2_w, fc2_b, out, smd);
}

extern "C" void kernel_launch(void* const* d_in, const int* in_sizes, int n_in,
                              void* d_out, int out_size, void* d_ws, size_t ws_size,
                              hipStream_t stream) {
    const void* x     = d_in[0];
    const void* adj   = d_in[1];
    const void* W_h   = d_in[2];
    const void* a_h   = d_in[3];
    const void* W_o   = d_in[4];
    const void* a_o   = d_in[5];
    const void* fc1_w = d_in[6];
    const void* fc1_b = d_in[7];
    const void* fc2_w = d_in[8];
    const void* fc2_b = d_in[9];
    float* out = (float*)d_out;

    char* ws = (char*)d_ws;                         // all offsets 16B-aligned
    int*   nbr   = (int*)(ws + 0);                  //  2,560,000 B
    int*   deg   = (int*)(ws + 2560000);            //     20,000 B
    float* Wh    = (float*)(ws + 2580000);          // 10,240,000 B (node-major [n][512])
    float* f1    = (float*)(ws + 12820000);         //    160,000 B
    float* f2    = (float*)(ws + 12980000);         //    160,000 B
    float* h1    = (float*)(ws + 13140000);         // 10,240,000 B
    float* Wh2   = (float*)(ws + 23380000);         //  1,280,000 B
    float* g1    = (float*)(ws + 24660000);         //     20,000 B
    float* g2    = (float*)(ws + 24680000);         //     20,000 B
    u16*   xc    = (u16*)(ws + 24700000);           //  5,120,000 B
    u16*   whc   = (u16*)(ws + 29820000);           //    524,288 B (MFMA fragment order)
    float* a_hc  = (float*)(ws + 30344288);         //      4,096 B
    float* W_oc  = (float*)(ws + 30348384);         //    131,072 B
    float* a_oc  = (float*)(ws + 30479456);         //        512 B
    float* f1wc  = (float*)(ws + 30479968);         //     51,200 B
    float* f1bc  = (float*)(ws + 30531168);         //        800 B
    float* f2wc  = (float*)(ws + 30531968);         //     32,000 B
    float* f2bc  = (float*)(ws + 30563968);         //        160 B
    u32*   bar   = (u32*)(ws + 30564128);           //         32 B  (total ~30.6 MB)

    // one-time: pick fused grid so ALL blocks are co-resident (homemade grid barrier)
    static int g_nblk = -1;
    if (g_nblk < 0) {
        int occ = 0, dev = 0;
        hipDeviceProp_t prop;
        hipError_t e1 = hipOccupancyMaxActiveBlocksPerMultiprocessor(&occ, fused, 256, 0);
        hipError_t e2 = hipGetDevice(&dev);
        hipError_t e3 = hipGetDeviceProperties(&prop, dev);
        if (e1 == hipSuccess && e2 == hipSuccess && e3 == hipSuccess && occ >= 1) {
            long nb = (long)occ * (long)prop.multiProcessorCount;
            g_nblk = (int)(nb > FUSED_MAXBLK ? FUSED_MAXBLK : nb);
        } else {
            g_nblk = 0;
        }
        if (g_nblk < 64) g_nblk = 0;               // degenerate occupancy: use fallback
    }

    if (g_nblk > 0) {
        hipMemsetAsync(bar, 0, 32, stream);        // barrier counters (ws is poisoned)
        fused<<<g_nblk, 256, 0, stream>>>(x, adj, W_h, a_h, W_o, a_o,
                                          fc1_w, fc1_b, fc2_w, fc2_b,
                                          xc, whc, a_hc, W_oc, a_oc,
                                          f1wc, f1bc, f2wc, f2bc,
                                          nbr, deg, Wh, f1, f2, h1, Wh2, g1, g2,
                                          out, bar, g_nblk);
    } else {
        cvt_all<<<328, 256, 0, stream>>>(x, W_h, adj, a_h, W_o, a_o,
                                         fc1_w, fc1_b, fc2_w, fc2_b,
                                         xc, whc, a_hc, W_oc, a_oc,
                                         f1wc, f1bc, f2wc, f2bc);
        gemm1_f<<<G1_BLKS + BM_BLKS, 256, 0, stream>>>((const bf16_t*)xc, (const bf16_t*)whc,
                                                       a_hc, adj, nbr, deg, Wh, f1, f2);
        agg1f<<<NN, 256, 0, stream>>>(nbr, deg, Wh, f1, f2, h1);
        gemm2_4<<<NN / 4, 256, 0, stream>>>(h1, W_oc, a_oc, Wh2, g1, g2);
        agg2_mlp<<<NN / 4, 256, 0, stream>>>(Wh2, g1, g2, nbr, deg,
                                             f1wc, f1bc, f2wc, f2bc, out);
    }
}

// Round 4
// 286.765 us; speedup vs baseline: 2.4134x; 2.4134x over previous
//
#include <hip/hip_runtime.h>

typedef unsigned short u16;
typedef unsigned int u32;
typedef unsigned long long u64;
typedef __bf16 bf16_t;
typedef __bf16 bf16x8 __attribute__((ext_vector_type(8)));
typedef u16 u16x8 __attribute__((ext_vector_type(8)));
typedef float f32x4 __attribute__((ext_vector_type(4)));
typedef u32 u32x4 __attribute__((ext_vector_type(4)));   // native vector: OK for NT builtins

#define NN 5000
#define NF 512
#define NH 64
#define HEADS 8
#define NCLS 40
#define CAP 128
#define LRELU 0.2f

#define BM_BLKS 1250                 // adj items: 4 waves/block, wave per adj row
#define G1_BLKS (79 * HEADS)         // 632 GEMM items
#define PRM_BLKS 8                   // params-copy items
#define K1_GRID (BM_BLKS + G1_BLKS + PRM_BLKS)   // 1890

// ---- dtype probe: adj[0][0]==1.0 always (self-loop). fp32 word0=0x3F800000 (low16==0);
// ---- packed-bf16 word0 low half = 0x3F80 != 0. (fp32 path taken on this harness.)
__device__ __forceinline__ bool adj_is_bf16(const void* adj) {
    return ((*(const u32*)adj) & 0xFFFFu) != 0u;
}
__device__ __forceinline__ float up_bf16(u16 h) {
    return __uint_as_float((u32)h << 16);
}
__device__ __forceinline__ float in_f32(const void* p, int idx, bool isb) {
    return isb ? up_bf16(((const u16*)p)[idx]) : ((const float*)p)[idx];
}
__device__ __forceinline__ u32x4 ntload4(const void* p, int idx) {
    return __builtin_nontemporal_load(((const u32x4*)p) + idx);
}
union U8cast { u16x8 u; bf16x8 b; };

// =============== K1: GEMM (in-register convert) + adj->nbr decode + params copy ===========
// GEMM: Wh = x @ W_h (bf16 MFMA, inputs converted in-block from raw fp32/bf16) + f1/f2
// epilogue. C/D mapping row=(lane>>4)*4+r, col=lane&15. Wh NODE-MAJOR [n][h*64+o].
// adj items stream 100 MB HBM overlapped with the GEMM; decode emits nbr/deg directly.
// params items copy/convert the small weights for K3/K4. All item types are independent.
__global__ __launch_bounds__(256) void gemm1_f(const void* __restrict__ x,
                                               const void* __restrict__ W_h,
                                               const void* __restrict__ a_h,
                                               const void* __restrict__ adj,
                                               const void* W_o, const void* a_o,
                                               const void* f1w, const void* f1b,
                                               const void* f2w, const void* f2b,
                                               int* __restrict__ nbr, int* __restrict__ deg,
                                               float* __restrict__ Wh,
                                               float* __restrict__ f1,
                                               float* __restrict__ f2,
                                               float* W_oc, float* a_oc,
                                               float* f1wc, float* f1bc,
                                               float* f2wc, float* f2bc) {
    const bool isb = adj_is_bf16(adj);
    const int lane = threadIdx.x & 63;
    const int wid  = threadIdx.x >> 6;
    const int b = blockIdx.x;

    if (b < BM_BLKS) {
        // ---- adjacency -> neighbor lists: wave per row, NT streaming reads ----
        const int r = b * 4 + wid;                           // exact 5000
        u64 my0 = 0ull, my1 = 0ull;                          // lane holds word lane, lane+64
        if (!isb) {
            const float* row = (const float*)adj + (size_t)r * NN;     // 1250 u32x4 chunks
            #pragma unroll
            for (int pass = 0; pass < 2; ++pass) {
                u32x4 v[10];
                #pragma unroll
                for (int k = 0; k < 10; ++k) {
                    int c = (pass * 10 + k) * 64 + lane;
                    v[k] = (c < 1250) ? ntload4(row, c) : (u32x4){0u, 0u, 0u, 0u};
                }
                #pragma unroll
                for (int k = 0; k < 10; ++k) {
                    int i = pass * 10 + k;
                    #pragma unroll
                    for (int j = 0; j < 4; ++j) {
                        u64 m = __ballot(v[k][j] != 0u);     // wave-uniform
                        int w = i * 4 + j;
                        if (w == lane)      my0 = m;
                        if (w == lane + 64) my1 = m;
                    }
                }
            }
        } else {
            const u16* row = (const u16*)adj + (size_t)r * NN;         // 625 u32x4 chunks
            u32x4 v[10];
            #pragma unroll
            for (int k = 0; k < 10; ++k) {
                int c = k * 64 + lane;
                v[k] = (c < 625) ? ntload4(row, c) : (u32x4){0u, 0u, 0u, 0u};
            }
            #pragma unroll
            for (int k = 0; k < 10; ++k) {
                #pragma unroll
                for (int j = 0; j < 4; ++j) {
                    u64 mlo = __ballot((v[k][j] & 0xFFFFu) != 0u);
                    u64 mhi = __ballot((v[k][j] >> 16) != 0u);
                    int wl = k * 8 + 2 * j, wh = wl + 1;
                    if (wl == lane)      my0 = mlo;
                    if (wl == lane + 64) my1 = mlo;
                    if (wh == lane)      my0 = mhi;
                    if (wh == lane + 64) my1 = mhi;
                }
            }
        }
        // ---- decode: popc prefix-scan over 128 lane-words, emit global neighbor list ----
        int* nrow = nbr + (size_t)r * CAP;
        int pc = __popcll(my0);
        int scan = pc;
        #pragma unroll
        for (int o = 1; o < 64; o <<= 1) {
            int t2 = __shfl_up(scan, o);
            if (lane >= o) scan += t2;
        }
        int off = scan - pc;                                 // exclusive prefix
        {
            const int w = lane;
            u64 mw = my0;
            while (mw) {
                int bb = __ffsll(mw) - 1;
                mw &= mw - 1;
                int elem = !isb ? ((w >> 2) * 64 + bb) * 4 + (w & 3)
                                : ((w >> 3) * 64 + bb) * 8 + (w & 7);
                if (off < CAP) nrow[off] = elem;
                ++off;
            }
        }
        const int base = __shfl(scan, 63);
        int pc1 = __popcll(my1);
        int scan1 = pc1;
        #pragma unroll
        for (int o = 1; o < 64; o <<= 1) {
            int t2 = __shfl_up(scan1, o);
            if (lane >= o) scan1 += t2;
        }
        int off1 = base + scan1 - pc1;
        {
            const int w = lane + 64;
            u64 mw = my1;
            while (mw) {
                int bb = __ffsll(mw) - 1;
                mw &= mw - 1;
                int elem = !isb ? ((w >> 2) * 64 + bb) * 4 + (w & 3)
                                : ((w >> 3) * 64 + bb) * 8 + (w & 7);
                if (off1 < CAP) nrow[off1] = elem;
                ++off1;
            }
        }
        const int total = base + __shfl(scan1, 63);
        if (lane == 0) deg[r] = total < CAP ? total : CAP;
        return;
    }

    if (b >= BM_BLKS + G1_BLKS) {
        // ---- params copy/convert (small weights for K3/K4) ----
        const int s1 = HEADS * NH * NH, s2 = 2 * NH,
                  s3 = NH * 200, s4 = 200, s5 = 200 * NCLS, s6 = NCLS;
        const int total = s1 + s2 + s3 + s4 + s5 + s6;       // 53,936
        const int pb = b - (BM_BLKS + G1_BLKS);
        for (int i = pb * 256 + threadIdx.x; i < total; i += PRM_BLKS * 256) {
            const void* src; float* dst; int off = i;
            if (off < s1) { src = W_o;  dst = W_oc; }
            else if ((off -= s1) < s2) { src = a_o;  dst = a_oc; }
            else if ((off -= s2) < s3) { src = f1w;  dst = f1wc; }
            else if ((off -= s3) < s4) { src = f1b;  dst = f1bc; }
            else if ((off -= s4) < s5) { src = f2w;  dst = f2wc; }
            else { off -= s5;           src = f2b;  dst = f2bc; }
            dst[off] = isb ? up_bf16(((const u16*)src)[off]) : ((const float*)src)[off];
        }
        return;
    }

    // ---- GEMM item ----
    const int g = b - BM_BLKS;
    const int rg = g % 79;                // 79*64 = 5056 rows, guarded
    const int h  = g / 79;
    const int quad = lane >> 4;
    const int lr   = lane & 15;
    const int kq   = quad * 8;
    const int nCol = wid * 16 + lr;
    __shared__ float f1s[4][64], f2s[4][64];

    // B fragments from raw W_h: element (s*32+kq+j, nCol) of head h. fp32 scalar loads are
    // 16-consecutive-float runs per quad (no over-fetch); head tile is L2-resident (x79 reuse).
    bf16x8 bfrag[16];
    if (!isb) {
        const float* Bh = (const float*)W_h + (size_t)h * NF * NH;
        #pragma unroll
        for (int s = 0; s < 16; ++s) {
            bf16x8 bb;
            #pragma unroll
            for (int j = 0; j < 8; ++j) bb[j] = (bf16_t)Bh[(s * 32 + kq + j) * NH + nCol];
            bfrag[s] = bb;
        }
    } else {
        const u16* Bh = (const u16*)W_h + (size_t)h * NF * NH;
        #pragma unroll
        for (int s = 0; s < 16; ++s) {
            U8cast cc;
            #pragma unroll
            for (int j = 0; j < 8; ++j) cc.u[j] = Bh[(s * 32 + kq + j) * NH + nCol];
            bfrag[s] = cc.b;
        }
    }
    const float a1c = in_f32(a_h, h * 128 + nCol, isb);
    const float a2c = in_f32(a_h, h * 128 + NH + nCol, isb);

    for (int t = 0; t < 4; ++t) {
        const int rb = rg * 64 + t * 16;
        int row  = rb + lr;
        int rowc = row < NN ? row : NN - 1;
        f32x4 acc = {0.f, 0.f, 0.f, 0.f};
        if (!isb) {
            const float* xp = (const float*)x + (size_t)rowc * NF + kq;
            #pragma unroll
            for (int s = 0; s < 16; ++s) {
                float4 lo = *(const float4*)(xp + s * 32);
                float4 hi = *(const float4*)(xp + s * 32 + 4);
                bf16x8 a;
                a[0] = (bf16_t)lo.x; a[1] = (bf16_t)lo.y; a[2] = (bf16_t)lo.z; a[3] = (bf16_t)lo.w;
                a[4] = (bf16_t)hi.x; a[5] = (bf16_t)hi.y; a[6] = (bf16_t)hi.z; a[7] = (bf16_t)hi.w;
                acc = __builtin_amdgcn_mfma_f32_16x16x32_bf16(a, bfrag[s], acc, 0, 0, 0);
            }
        } else {
            const u16* xp = (const u16*)x + (size_t)rowc * NF + kq;
            #pragma unroll
            for (int s = 0; s < 16; ++s) {
                U8cast cc;
                cc.u = *(const u16x8*)(xp + s * 32);
                acc = __builtin_amdgcn_mfma_f32_16x16x32_bf16(cc.b, bfrag[s], acc, 0, 0, 0);
            }
        }
        #pragma unroll
        for (int r = 0; r < 4; ++r) {
            int gr = rb + quad * 4 + r;
            if (gr < NN) Wh[(size_t)gr * (HEADS * NH) + h * NH + nCol] = acc[r];  // node-major
            float p1 = acc[r] * a1c, p2 = acc[r] * a2c;
            #pragma unroll
            for (int o = 8; o; o >>= 1) { p1 += __shfl_xor(p1, o); p2 += __shfl_xor(p2, o); }
            if (lr == 0) { f1s[wid][t * 16 + quad * 4 + r] = p1; f2s[wid][t * 16 + quad * 4 + r] = p2; }
        }
    }
    __syncthreads();
    if (wid == 0) {
        int gr = rg * 64 + lane;
        if (gr < NN) {
            f1[h * NN + gr] = f1s[0][lane] + f1s[1][lane] + f1s[2][lane] + f1s[3][lane];
            f2[h * NN + gr] = f2s[0][lane] + f2s[1][lane] + f2s[2][lane] + f2s[3][lane];
        }
    }
}

// ---------------- K2 agg1f: ALL-heads layer-1 attention, block/node ----------------
// Softmax per wave = heads (wid, wid+4); normalized alphas parked in LDS s_p[8][CAP].
// Gather: wave owns the contiguous 512B head-pair slice [wid*128, wid*128+128) of each
// neighbor row, read as ONE float2/lane (global_load_dwordx2); float2 stores.
__global__ __launch_bounds__(256) void agg1f(const int* __restrict__ nbr,
                                             const int* __restrict__ deg,
                                             const float* __restrict__ Wh,
                                             const float* __restrict__ f1,
                                             const float* __restrict__ f2,
                                             float* __restrict__ h1) {
    const int lane = threadIdx.x & 63;
    const int wid  = threadIdx.x >> 6;
    const int n = blockIdx.x;               // 5000 blocks
    __shared__ int s_nbr[CAP];
    __shared__ float s_p[8][CAP];
    const int d = deg[n];
    for (int i = threadIdx.x; i < d; i += 256) s_nbr[i] = nbr[(size_t)n * CAP + i];
    __syncthreads();

    const int ha = wid, hb = wid + 4;
    const int nb0 = (lane < d) ? s_nbr[lane] : 0;
    const int nb1 = (lane + 64 < d) ? s_nbr[lane + 64] : 0;
    const float f10 = f1[ha * NN + n], f11 = f1[hb * NN + n];
    const float* f2ha = f2 + (size_t)ha * NN;
    const float* f2hb = f2 + (size_t)hb * NN;

    float e00 = -INFINITY, e01 = -INFINITY, e10 = -INFINITY, e11 = -INFINITY;
    if (lane < d) {
        float a = f10 + f2ha[nb0]; e00 = a > 0.f ? a : LRELU * a;
        float b = f11 + f2hb[nb0]; e10 = b > 0.f ? b : LRELU * b;
    }
    if (lane + 64 < d) {
        float a = f10 + f2ha[nb1]; e01 = a > 0.f ? a : LRELU * a;
        float b = f11 + f2hb[nb1]; e11 = b > 0.f ? b : LRELU * b;
    }
    float mx0 = fmaxf(e00, e01), mx1 = fmaxf(e10, e11);
    #pragma unroll
    for (int o = 32; o; o >>= 1) {
        mx0 = fmaxf(mx0, __shfl_xor(mx0, o));
        mx1 = fmaxf(mx1, __shfl_xor(mx1, o));
    }
    float p00 = lane < d ? expf(e00 - mx0) : 0.f;
    float p01 = lane + 64 < d ? expf(e01 - mx0) : 0.f;
    float p10 = lane < d ? expf(e10 - mx1) : 0.f;
    float p11 = lane + 64 < d ? expf(e11 - mx1) : 0.f;
    float sm0 = p00 + p01, sm1 = p10 + p11;
    #pragma unroll
    for (int o = 32; o; o >>= 1) { sm0 += __shfl_xor(sm0, o); sm1 += __shfl_xor(sm1, o); }

    // fold 1/sum into alpha (reorder-safe): hv = sum(alpha_norm * w)
    const float i0 = 1.f / sm0, i1 = 1.f / sm1;
    s_p[ha][lane] = p00 * i0; s_p[ha][lane + 64] = p01 * i0;
    s_p[hb][lane] = p10 * i1; s_p[hb][lane + 64] = p11 * i1;
    __syncthreads();                        // gather reads other waves' alphas

    // gather: wave covers heads (2*wid, 2*wid+1); lane -> col pair 2*lane of 128
    const float* ap = s_p[2 * wid + (lane >> 5)];
    const float* wp = Wh + wid * 128 + 2 * lane;
    float A0x = 0.f, A0y = 0.f, A1x = 0.f, A1y = 0.f;
    float A2x = 0.f, A2y = 0.f, A3x = 0.f, A3y = 0.f;
    int j = 0;
    for (; j + 8 <= d; j += 8) {
        #pragma unroll
        for (int u = 0; u < 8; ++u) {
            const float2 v = *(const float2*)(wp + (size_t)s_nbr[j + u] * (HEADS * NH));
            const float a = ap[j + u];
            if ((u & 3) == 0)      { A0x += a * v.x; A0y += a * v.y; }
            else if ((u & 3) == 1) { A1x += a * v.x; A1y += a * v.y; }
            else if ((u & 3) == 2) { A2x += a * v.x; A2y += a * v.y; }
            else                   { A3x += a * v.x; A3y += a * v.y; }
        }
    }
    for (; j < d; ++j) {
        const float2 v = *(const float2*)(wp + (size_t)s_nbr[j] * (HEADS * NH));
        const float a = ap[j];
        A0x += a * v.x; A0y += a * v.y;
    }
    float hx = A0x + A1x + A2x + A3x;                        // already normalized
    float hy = A0y + A1y + A2y + A3y;
    hx = hx > 0.f ? hx : expf(hx) - 1.f;                     // ELU
    hy = hy > 0.f ? hy : expf(hy) - 1.f;
    *(float2*)(h1 + (size_t)n * (HEADS * NH) + wid * 128 + 2 * lane) = make_float2(hx, hy);
}

// ---------------- K3: Wh2 = h1 @ W_o + g1/g2 — 4 nodes/block, W_o read once/block --------
__global__ __launch_bounds__(256) void gemm2_4(const float* __restrict__ h1,
                                               const float* __restrict__ W_o,
                                               const float* __restrict__ a_o,
                                               float* __restrict__ Wh2,
                                               float* __restrict__ g1,
                                               float* __restrict__ g2) {
    const int t = threadIdx.x;
    const int n0 = blockIdx.x * 4;          // exact 5000
    __shared__ float sh[4 * 512];           // 4 nodes' h1
    __shared__ float ps[4][4][64];          // (k-part, node, o)
    const float4* src = (const float4*)(h1 + (size_t)n0 * 512);
    ((float4*)sh)[t]       = src[t];
    ((float4*)sh)[t + 256] = src[t + 256];
    __syncthreads();
    const int o = t & 63, part = t >> 6;    // each thread: one o, one 128-wide k-slice, 4 nodes
    float a0 = 0.f, a1 = 0.f, a2 = 0.f, a3 = 0.f;
    const float* wo = W_o + part * 128 * 64 + o;
    const float* s0 = sh + part * 128;
    #pragma unroll 4
    for (int f = 0; f < 128; ++f) {
        float w = wo[f * 64];               // loaded once, used 4x
        a0 += s0[f] * w; a1 += s0[512 + f] * w; a2 += s0[1024 + f] * w; a3 += s0[1536 + f] * w;
    }
    ps[part][0][o] = a0; ps[part][1][o] = a1; ps[part][2][o] = a2; ps[part][3][o] = a3;
    __syncthreads();
    const int nd = t >> 6;                  // wave = node; lane = o
    float w2 = ps[0][nd][o] + ps[1][nd][o] + ps[2][nd][o] + ps[3][nd][o];
    Wh2[(size_t)(n0 + nd) * 64 + o] = w2;
    float p1 = w2 * a_o[o], p2 = w2 * a_o[64 + o];
    #pragma unroll
    for (int s = 32; s; s >>= 1) { p1 += __shfl_xor(p1, s); p2 += __shfl_xor(p2, s); }
    if (o == 0) { g1[n0 + nd] = p1; g2[n0 + nd] = p2; }
}

// ---------------- K4: layer-2 attention + aggregation + MLP head ----------------
__global__ __launch_bounds__(256) void agg2_mlp(const float* __restrict__ Wh2,
                                                const float* __restrict__ g1,
                                                const float* __restrict__ g2,
                                                const int* __restrict__ nbr,
                                                const int* __restrict__ deg,
                                                const float* __restrict__ fc1_w,
                                                const float* __restrict__ fc1_b,
                                                const float* __restrict__ fc2_w,
                                                const float* __restrict__ fc2_b,
                                                float* __restrict__ out) {
    const int lane = threadIdx.x & 63;
    const int wid  = threadIdx.x >> 6;
    const int t = threadIdx.x;
    const int n0 = blockIdx.x * 4;          // exact 5000
    const int n = n0 + wid;                 // gather phase: wave = node
    __shared__ float s_alpha[4][CAP];
    __shared__ int   s_nbr[4][CAP];
    __shared__ float s_h2[4][NH];
    __shared__ float s_h3[4][200];
    __shared__ float ps2[2][4][NCLS];
    const int d = deg[n];
    const int* nb = nbr + (size_t)n * CAP;
    const float gn = g1[n];

    float mx = -INFINITY;
    for (int j = lane; j < d; j += 64) {
        int m = nb[j];
        s_nbr[wid][j] = m;
        float e = gn + g2[m];
        e = e > 0.f ? e : LRELU * e;
        s_alpha[wid][j] = e;
        mx = fmaxf(mx, e);
    }
    #pragma unroll
    for (int o = 32; o; o >>= 1) mx = fmaxf(mx, __shfl_xor(mx, o));
    float sm = 0.f;
    for (int j = lane; j < d; j += 64) {
        float p = expf(s_alpha[wid][j] - mx);
        s_alpha[wid][j] = p;
        sm += p;
    }
    #pragma unroll
    for (int o = 32; o; o >>= 1) sm += __shfl_xor(sm, o);

    float acc0 = 0.f, acc1 = 0.f, acc2 = 0.f, acc3 = 0.f;
    int j = 0;
    for (; j + 4 <= d; j += 4) {
        acc0 += s_alpha[wid][j]     * Wh2[(size_t)s_nbr[wid][j]     * NH + lane];
        acc1 += s_alpha[wid][j + 1] * Wh2[(size_t)s_nbr[wid][j + 1] * NH + lane];
        acc2 += s_alpha[wid][j + 2] * Wh2[(size_t)s_nbr[wid][j + 2] * NH + lane];
        acc3 += s_alpha[wid][j + 3] * Wh2[(size_t)s_nbr[wid][j + 3] * NH + lane];
    }
    for (; j < d; ++j) acc0 += s_alpha[wid][j] * Wh2[(size_t)s_nbr[wid][j] * NH + lane];
    s_h2[wid][lane] = (acc0 + acc1 + acc2 + acc3) / sm;
    __syncthreads();

    // fc1: 200 threads x 4 nodes, fc1_w read once/block
    if (t < 200) {
        float b0 = 0.f, b1 = 0.f, b2 = 0.f, b3 = 0.f;
        #pragma unroll 4
        for (int f = 0; f < NH; ++f) {
            float w = fc1_w[f * 200 + t];
            b0 += s_h2[0][f] * w; b1 += s_h2[1][f] * w; b2 += s_h2[2][f] * w; b3 += s_h2[3][f] * w;
        }
        float bb = fc1_b[t];
        b0 += bb; b1 += bb; b2 += bb; b3 += bb;
        s_h3[0][t] = b0 > 0.f ? b0 : expf(b0) - 1.f;
        s_h3[1][t] = b1 > 0.f ? b1 : expf(b1) - 1.f;
        s_h3[2][t] = b2 > 0.f ? b2 : expf(b2) - 1.f;
        s_h3[3][t] = b3 > 0.f ? b3 : expf(b3) - 1.f;
    }
    __syncthreads();

    // fc2: 80 threads = (f-half, class) x 4 nodes; fc2_w read 2x/block
    if (t < 80) {
        const int o = t % 40, fh = t / 40;
        float c0 = 0.f, c1 = 0.f, c2 = 0.f, c3 = 0.f;
        #pragma unroll 4
        for (int f = fh * 100; f < fh * 100 + 100; ++f) {
            float w = fc2_w[f * NCLS + o];
            c0 += s_h3[0][f] * w; c1 += s_h3[1][f] * w; c2 += s_h3[2][f] * w; c3 += s_h3[3][f] * w;
        }
        ps2[fh][0][o] = c0; ps2[fh][1][o] = c1; ps2[fh][2][o] = c2; ps2[fh][3][o] = c3;
    }
    __syncthreads();
    if (t < 160) {
        const int nd = t / 40, o = t % 40;
        out[(size_t)(n0 + nd) * NCLS + o] = ps2[0][nd][o] + ps2[1][nd][o] + fc2_b[o];
    }
}

extern "C" void kernel_launch(void* const* d_in, const int* in_sizes, int n_in,
                              void* d_out, int out_size, void* d_ws, size_t ws_size,
                              hipStream_t stream) {
    const void* x     = d_in[0];
    const void* adj   = d_in[1];
    const void* W_h   = d_in[2];
    const void* a_h   = d_in[3];
    const void* W_o   = d_in[4];
    const void* a_o   = d_in[5];
    const void* fc1_w = d_in[6];
    const void* fc1_b = d_in[7];
    const void* fc2_w = d_in[8];
    const void* fc2_b = d_in[9];
    float* out = (float*)d_out;

    char* ws = (char*)d_ws;                         // all offsets 16B-aligned
    int*   nbr   = (int*)(ws + 0);                  //  2,560,000 B
    int*   deg   = (int*)(ws + 2560000);            //     20,000 B
    float* Wh    = (float*)(ws + 2580000);          // 10,240,000 B (node-major [n][512])
    float* f1    = (float*)(ws + 12820000);         //    160,000 B
    float* f2    = (float*)(ws + 12980000);         //    160,000 B
    float* h1    = (float*)(ws + 13140000);         // 10,240,000 B
    float* Wh2   = (float*)(ws + 23380000);         //  1,280,000 B
    float* g1    = (float*)(ws + 24660000);         //     20,000 B
    float* g2    = (float*)(ws + 24680000);         //     20,000 B
    float* W_oc  = (float*)(ws + 24700000);         //    131,072 B
    float* a_oc  = (float*)(ws + 24831072);         //        512 B
    float* f1wc  = (float*)(ws + 24831584);         //     51,200 B
    float* f1bc  = (float*)(ws + 24882784);         //        800 B
    float* f2wc  = (float*)(ws + 24883584);         //     32,000 B
    float* f2bc  = (float*)(ws + 24915584);         //        160 B  (total ~24.9 MB)

    gemm1_f<<<K1_GRID, 256, 0, stream>>>(x, W_h, a_h, adj,
                                         W_o, a_o, fc1_w, fc1_b, fc2_w, fc2_b,
                                         nbr, deg, Wh, f1, f2,
                                         W_oc, a_oc, f1wc, f1bc, f2wc, f2bc);
    agg1f<<<NN, 256, 0, stream>>>(nbr, deg, Wh, f1, f2, h1);
    gemm2_4<<<NN / 4, 256, 0, stream>>>(h1, W_oc, a_oc, Wh2, g1, g2);
    agg2_mlp<<<NN / 4, 256, 0, stream>>>(Wh2, g1, g2, nbr, deg,
                                         f1wc, f1bc, f2wc, f2bc, out);
}